// Round 12
// baseline (470.029 us; speedup 1.0000x reference)
//
#include <hip/hip_runtime.h>

#define DIN 128
#define DH  64
#define PAD 64
#define PLACE_NB 64   // place blocks; each owns ceil(n/64) dst (LDS counters)

typedef unsigned int u32x4 __attribute__((ext_vector_type(4)));

// ---------------- input-format detection ----------------
__device__ __forceinline__ bool detect_i64(const int* __restrict__ ei) {
  bool i64 = true;
#pragma unroll
  for (int j = 1; j < 32; j += 2) i64 = i64 && (ei[j] == 0);
  return i64;
}
__device__ __forceinline__ bool detect_m8(const unsigned int* __restrict__ mask) {
  return (mask[0] == 0x01010101u) && (mask[1] == 0x01010101u);
}

// ---------------- compact: edge e -> u32 record (dst<<16 | src) --------------
// Valid because n = 50000 < 65536. Masked-out edges -> 0xFFFFFFFF (dst field
// 65535 >= n, outside every owner range).
__global__ __launch_bounds__(256) void k_compact(const int* __restrict__ ei,
                                                 const unsigned int* __restrict__ mask,
                                                 int E, unsigned int* __restrict__ rec) {
  const bool i64 = detect_i64(ei);
  const bool m8  = detect_m8(mask);
  const int i = (blockIdx.x * 256 + threadIdx.x) * 4;
  if (i >= E) return;
  const bool vec = (i + 4 <= E) && ((E & 3) == 0);   // alignment of &ei[E+i]

  int s4[4], d4[4];
  unsigned int w4[4];
  if (vec) {
    if (i64) {
      int4 a0 = *(const int4*)&ei[2 * i];
      int4 a1 = *(const int4*)&ei[2 * i + 4];
      s4[0] = a0.x; s4[1] = a0.z; s4[2] = a1.x; s4[3] = a1.z;
      int4 b0 = *(const int4*)&ei[2 * (E + i)];
      int4 b1 = *(const int4*)&ei[2 * (E + i) + 4];
      d4[0] = b0.x; d4[1] = b0.z; d4[2] = b1.x; d4[3] = b1.z;
    } else {
      int4 a0 = *(const int4*)&ei[i];
      s4[0] = a0.x; s4[1] = a0.y; s4[2] = a0.z; s4[3] = a0.w;
      int4 b0 = *(const int4*)&ei[E + i];
      d4[0] = b0.x; d4[1] = b0.y; d4[2] = b0.z; d4[3] = b0.w;
    }
    if (m8) {
      unsigned int mw = mask[i >> 2];
      w4[0] = mw & 0xffu; w4[1] = (mw >> 8) & 0xffu;
      w4[2] = (mw >> 16) & 0xffu; w4[3] = (mw >> 24) & 0xffu;
    } else {
#pragma unroll
      for (int j = 0; j < 4; j++) w4[j] = mask[i + j];
    }
    uint4 r;
    r.x = w4[0] ? (((unsigned)d4[0] << 16) | (unsigned)s4[0]) : 0xFFFFFFFFu;
    r.y = w4[1] ? (((unsigned)d4[1] << 16) | (unsigned)s4[1]) : 0xFFFFFFFFu;
    r.z = w4[2] ? (((unsigned)d4[2] << 16) | (unsigned)s4[2]) : 0xFFFFFFFFu;
    r.w = w4[3] ? (((unsigned)d4[3] << 16) | (unsigned)s4[3]) : 0xFFFFFFFFu;
    *(uint4*)&rec[i] = r;
  } else {
    for (int j = i; j < min(i + 4, E); j++) {
      int s = i64 ? ei[2 * j] : ei[j];
      int d = i64 ? ei[2 * (E + j)] : ei[E + j];
      unsigned int wj = m8 ? (unsigned int)((const unsigned char*)mask)[j] : mask[j];
      rec[j] = wj ? (((unsigned)d << 16) | (unsigned)s) : 0xFFFFFFFFu;
    }
  }
}

// ---------------- fused: LDS-owned placement | gemm1 ----------------
// Place block b (< PLACE_NB) OWNS dst range [b*span,(b+1)*span): counters
// live in LDS (atomicAdd ~20cy, no global RMW -- the r6-r11 ~55us floor was
// 800K device-scope atomics). Each place block scans the whole 3.2 MB rec
// stream; 8 blocks/XCD share it through L2 (no nt-hint: reuse desired).
// pad writes confine to a 200 KB L2-local slice -> dense writeback.
// cnt flushed LDS->global once. Gemm blocks: 32-row tiles of g = x @ W1.
__global__ __launch_bounds__(256) void k_fused(const float* __restrict__ x,
                                               const float* __restrict__ W1,
                                               const unsigned int* __restrict__ rec,
                                               int E,
                                               unsigned int* __restrict__ cnt,
                                               int* __restrict__ pad,
                                               int* __restrict__ ovfbuf,
                                               unsigned int* __restrict__ ovfcnt,
                                               float* __restrict__ g, int n) {
  __shared__ float xs[32 * DIN];   // 16 KB; place branch reuses it as counters
  const int tid = threadIdx.x;

  if ((int)blockIdx.x < PLACE_NB) {
    // ---------------- placement branch (LDS counters, sole owner) ----------
    unsigned int* lcnt = (unsigned int*)xs;        // span words (<= 4096)
    const int span = (n + PLACE_NB - 1) / PLACE_NB;     // 782 for n=50000
    const int lo = (int)blockIdx.x * span;
    const unsigned int myspan =
        (unsigned int)min(span, n - lo);           // last block clamps
    for (int i = tid; i < span; i += 256) lcnt[i] = 0u;
    __syncthreads();

    for (int e0 = tid * 4; e0 < E; e0 += 1024) {
      unsigned int r4[4];
      if (e0 + 4 <= E) {
        u32x4 r = *(const u32x4*)&rec[e0];
        r4[0] = r.x; r4[1] = r.y; r4[2] = r.z; r4[3] = r.w;
      } else {
#pragma unroll
        for (int j = 0; j < 4; j++)
          r4[j] = (e0 + j < E) ? rec[e0 + j] : 0xFFFFFFFFu;
      }
#pragma unroll
      for (int j = 0; j < 4; j++) {
        const unsigned int idx = (r4[j] >> 16) - (unsigned int)lo;
        if (idx < myspan) {
          const int s = (int)(r4[j] & 0xFFFFu);
          unsigned int pos = atomicAdd(&lcnt[idx], 1u);   // LDS atomic
          if (pos < (unsigned)PAD) {
            pad[(size_t)(lo + (int)idx) * PAD + pos] = s;
          } else {                                        // rare spill
            unsigned int o = atomicAdd(ovfcnt, 1u);
            ovfbuf[2 * o] = s; ovfbuf[2 * o + 1] = lo + (int)idx;
          }
        }
      }
    }
    __syncthreads();
    for (int i = tid; i < (int)myspan; i += 256) cnt[lo + i] = lcnt[i];
    return;
  }

  // ---------------- gemm1 branch: tile t = blockIdx - PLACE_NB ----------------
  const int t = (int)blockIdx.x - PLACE_NB;
  const int row0 = t * 32;
  if (row0 >= n) return;
  const int nrows = min(32, n - row0);
  for (int i = tid * 4; i < nrows * DIN; i += 1024)
    *(float4*)&xs[i] = *(const float4*)&x[(size_t)row0 * DIN + i];
  __syncthreads();
  const int col = tid & 63;
  const int wv  = tid >> 6;
  float a[8];
#pragma unroll
  for (int i = 0; i < 8; i++) a[i] = 0.f;
#pragma unroll 4
  for (int k = 0; k < DIN; k++) {
    float w = W1[k * DH + col];              // global, coalesced, L1-hot
#pragma unroll
    for (int i = 0; i < 8; i++)
      a[i] = fmaf(xs[(wv * 8 + i) * DIN + k], w, a[i]);  // LDS broadcast
  }
#pragma unroll
  for (int i = 0; i < 8; i++) {
    int r = row0 + wv * 8 + i;
    if (r < n) g[(size_t)r * DH + col] = a[i];
  }
}

// ---------------- scale: dinv[v] = rsqrt(cnt+1); g[v] *= dinv[v] ------------
__global__ __launch_bounds__(256) void k_scale(const unsigned int* __restrict__ cnt,
                                               float* __restrict__ g,
                                               float* __restrict__ dinv, int n) {
  const int i0 = (blockIdx.x * 256 + threadIdx.x) * 4;
  if (i0 >= n * DH) return;
  const int v = i0 >> 6;
  const float dv = rsqrtf((float)cnt[v] + 1.0f);  // +1 = self loop
  if ((i0 & 63) == 0) dinv[v] = dv;
  float4 t = *(float4*)&g[i0];
  t.x *= dv; t.y *= dv; t.z *= dv; t.w *= dv;
  *(float4*)&g[i0] = t;
}

// ---------------- agg(layer1) + relu/bias + gemm2, barrier-free -------------
// One wave per node. Lane holds u2[lane]; 64x64 matvec in-register via
// __shfl broadcast; W2 from global (16 KB, L1-hot). Zero LDS/barriers.
__global__ __launch_bounds__(256) void k_aggmid(const float* __restrict__ g,
                                                const unsigned int* __restrict__ cnt,
                                                const int* __restrict__ pad,
                                                const float* __restrict__ dinv,
                                                const float* __restrict__ b1,
                                                const float* __restrict__ W2,
                                                const int* __restrict__ ovfbuf,
                                                const unsigned int* __restrict__ ovfcnt,
                                                float* __restrict__ g2, int n) {
  const int v = (blockIdx.x * 256 + threadIdx.x) >> 6;
  if (v >= n) return;
  const int lane = threadIdx.x & 63;
  const float dv = dinv[v];
  const int len = min((int)cnt[v], PAD);
  const int* row = pad + (size_t)v * PAD;
  float a = g[(size_t)v * DH + lane];          // self-loop term (prescaled)
  int e = 0;
  for (; e + 16 <= len; e += 16) {             // 16-deep gather MLP
    int s[16];
#pragma unroll
    for (int j = 0; j < 16; j++) s[j] = row[e + j];
    float x16[16];
#pragma unroll
    for (int j = 0; j < 16; j++) x16[j] = g[(size_t)s[j] * DH + lane];
#pragma unroll
    for (int j = 0; j < 16; j++) a += x16[j];
  }
  for (; e + 8 <= len; e += 8) {
    int s[8];
#pragma unroll
    for (int j = 0; j < 8; j++) s[j] = row[e + j];
    float x8[8];
#pragma unroll
    for (int j = 0; j < 8; j++) x8[j] = g[(size_t)s[j] * DH + lane];
#pragma unroll
    for (int j = 0; j < 8; j++) a += x8[j];
  }
  for (; e + 4 <= len; e += 4) {
    int s0 = row[e], s1 = row[e + 1], s2 = row[e + 2], s3 = row[e + 3];
    float x0 = g[(size_t)s0 * DH + lane];
    float x1 = g[(size_t)s1 * DH + lane];
    float x2 = g[(size_t)s2 * DH + lane];
    float x3 = g[(size_t)s3 * DH + lane];
    a += x0 + x1 + x2 + x3;
  }
  for (; e < len; e++) a += g[(size_t)row[e] * DH + lane];
  unsigned int nov = *ovfcnt;                  // normally 0: one scalar load
  if (nov != 0u) {                             // pathological high-degree path
    for (unsigned int j = 0; j < nov; j++) {
      if (ovfbuf[2 * j + 1] == v) a += g[(size_t)ovfbuf[2 * j] * DH + lane];
    }
  }
  const float u2 = dv * fmaxf(fmaf(dv, a, b1[lane]), 0.f);  // premultiplied

  float acc = 0.f;
#pragma unroll
  for (int k = 0; k < DH; k++)
    acc = fmaf(__shfl(u2, k, 64), W2[k * DH + lane], acc);
  g2[(size_t)v * DH + lane] = acc;
}

// ---------------- agg(layer2): out = dv*(g2[v] + sum g2[s]) + b2 ------------
__global__ __launch_bounds__(256) void k_aggout(const float* __restrict__ g2,
                                                const unsigned int* __restrict__ cnt,
                                                const int* __restrict__ pad,
                                                const float* __restrict__ dinv,
                                                const float* __restrict__ b2,
                                                const int* __restrict__ ovfbuf,
                                                const unsigned int* __restrict__ ovfcnt,
                                                float* __restrict__ out, int n) {
  const int v = (blockIdx.x * 256 + threadIdx.x) >> 6;
  if (v >= n) return;
  const int lane = threadIdx.x & 63;
  const float dv = dinv[v];
  const int len = min((int)cnt[v], PAD);
  const int* row = pad + (size_t)v * PAD;
  float a = g2[(size_t)v * DH + lane];         // self-loop term (pre-scaled)
  int e = 0;
  for (; e + 16 <= len; e += 16) {             // 16-deep gather MLP
    int s[16];
#pragma unroll
    for (int j = 0; j < 16; j++) s[j] = row[e + j];
    float x16[16];
#pragma unroll
    for (int j = 0; j < 16; j++) x16[j] = g2[(size_t)s[j] * DH + lane];
#pragma unroll
    for (int j = 0; j < 16; j++) a += x16[j];
  }
  for (; e + 8 <= len; e += 8) {
    int s[8];
#pragma unroll
    for (int j = 0; j < 8; j++) s[j] = row[e + j];
    float x8[8];
#pragma unroll
    for (int j = 0; j < 8; j++) x8[j] = g2[(size_t)s[j] * DH + lane];
#pragma unroll
    for (int j = 0; j < 8; j++) a += x8[j];
  }
  for (; e + 4 <= len; e += 4) {
    int s0 = row[e], s1 = row[e + 1], s2 = row[e + 2], s3 = row[e + 3];
    float x0 = g2[(size_t)s0 * DH + lane];
    float x1 = g2[(size_t)s1 * DH + lane];
    float x2 = g2[(size_t)s2 * DH + lane];
    float x3 = g2[(size_t)s3 * DH + lane];
    a += x0 + x1 + x2 + x3;
  }
  for (; e < len; e++) a += g2[(size_t)row[e] * DH + lane];
  unsigned int nov = *ovfcnt;
  if (nov != 0u) {
    for (unsigned int j = 0; j < nov; j++) {
      if (ovfbuf[2 * j + 1] == v) a += g2[(size_t)ovfbuf[2 * j] * DH + lane];
    }
  }
  out[(size_t)v * DH + lane] = fmaf(dv, a, b2[lane]);
}

extern "C" void kernel_launch(void* const* d_in, const int* in_sizes, int n_in,
                              void* d_out, int out_size, void* d_ws, size_t ws_size,
                              hipStream_t stream) {
  const float* x  = (const float*)d_in[0];
  const int* ei   = (const int*)d_in[1];
  const unsigned int* mask = (const unsigned int*)d_in[2];
  const float* W1 = (const float*)d_in[3];
  const float* b1 = (const float*)d_in[4];
  const float* W2 = (const float*)d_in[5];
  const float* b2 = (const float*)d_in[6];
  const int n = in_sizes[0] / DIN;     // 50000
  const int E = in_sizes[2];           // 800000

  char* w = (char*)d_ws;
  const size_t A   = 262144u;          // 256 KiB small-array slab
  const size_t BIG = 13631488u;        // 13 MiB >= n*PAD*4 = n*DH*4 = 12.8 MB
  const size_t REC = 4194304u;         // 4 MiB >= E*4 = 3.2 MB
  unsigned int* cnt    = (unsigned int*)(w);            // n counters
  unsigned int* ovfcnt = (unsigned int*)(w) + n;        // 1 word after cnt
  float*        dinv   = (float*)(w + A);               // n floats
  int*          pad    = (int*)(w + 2 * A);             // n*PAD ints
  float*        gbuf   = (float*)(w + 2 * A + BIG);     // g1 (prescaled in place)
  float*        g2buf  = (float*)(w + 2 * A + 2 * BIG); // layer-2 gemm output
  unsigned int* rec    = (unsigned int*)(w + 2 * A + 3 * BIG);        // compact edges
  int*          ovfbuf = (int*)(w + 2 * A + 3 * BIG + REC);           // spill

  (void)hipMemsetAsync(ovfcnt, 0, sizeof(unsigned int), stream);

  const int ntiles = (n + 31) / 32;             // 1563 gemm1 tiles
  const int aggBlocks = (n * 64 + 255) / 256;   // one wave per node

  // compact edge records (sequential streaming, ~5 us)
  k_compact<<<(E / 4 + 255) / 256, 256, 0, stream>>>(ei, mask, E, rec);
  // fused LDS-owned CSR build (no global atomics) + gemm1
  k_fused<<<PLACE_NB + ntiles, 256, 0, stream>>>(x, W1, rec, E, cnt, pad,
                                                 ovfbuf, ovfcnt, gbuf, n);
  // dinv + prescale g1 (streaming, ~7 us)
  k_scale<<<(n * DH / 4 + 255) / 256, 256, 0, stream>>>(cnt, gbuf, dinv, n);
  // layer 1 aggregation + bias/relu + gemm2, barrier-free (1 wave per node)
  k_aggmid<<<aggBlocks, 256, 0, stream>>>(gbuf, cnt, pad, dinv, b1, W2,
                                          ovfbuf, ovfcnt, g2buf, n);
  // layer 2 aggregation + b2 -> out
  k_aggout<<<aggBlocks, 256, 0, stream>>>(g2buf, cnt, pad, dinv, b2,
                                          ovfbuf, ovfcnt, (float*)d_out, n);
}

// Round 13
// 142.311 us; speedup vs baseline: 3.3028x; 3.3028x over previous
//
#include <hip/hip_runtime.h>

#define DIN 128
#define DH  64
#define PAD 64

// ---------------- input-format detection ----------------
__device__ __forceinline__ bool detect_i64(const int* __restrict__ ei) {
  bool i64 = true;
#pragma unroll
  for (int j = 1; j < 32; j += 2) i64 = i64 && (ei[j] == 0);
  return i64;
}
__device__ __forceinline__ bool detect_m8(const unsigned int* __restrict__ mask) {
  return (mask[0] == 0x01010101u) && (mask[1] == 0x01010101u);
}

// ---------------- fused: XCD-partitioned placement | gemm1 (r7 best) --------
// Place chunk (sub=blockIdx&7 == XCD under round-robin dispatch): handles dst
// range [sub*n/8,(sub+1)*n/8); loads only dst words up front, mask/src
// exec-masked for in-range edges. pos = atomicAdd(&cnt[d],1) builds padded
// CSR + degree in one pass. Floor = 800K device-scope atomic RMW (~55us,
// proven occupancy/cache/compaction-insensitive r4-r12); gemm1 rides under.
__global__ __launch_bounds__(256) void k_fused(const float* __restrict__ x,
                                               const float* __restrict__ W1,
                                               const int* __restrict__ ei,
                                               const unsigned int* __restrict__ mask,
                                               int E,
                                               unsigned int* __restrict__ cnt,
                                               int* __restrict__ pad,
                                               int* __restrict__ ovfbuf,
                                               unsigned int* __restrict__ ovfcnt,
                                               float* __restrict__ g,
                                               int n, int PC, int GC) {
  __shared__ float xs[32 * DIN];   // 16 KB (gemm branch only)
  const int tid = threadIdx.x;
  const int c   = (int)blockIdx.x >> 3;     // chunk index
  const int sub = (int)blockIdx.x & 7;      // position in chunk == XCD (heuristic)
  const int T = PC + GC;
  const int gemmBefore = (int)(((long long)c * GC) / T);
  const bool isGemm = (int)(((long long)(c + 1) * GC) / T) > gemmBefore;

  if (!isGemm) {
    // ---------------- placement branch: dst range r = sub ----------------
    const int pc = c - gemmBefore;          // place-chunk index in [0, PC)
    const int lo = (int)(((long long)sub * n) >> 3);
    const int hi = (int)(((long long)(sub + 1) * n) >> 3);
    const unsigned int span = (unsigned int)(hi - lo);
    const bool i64 = detect_i64(ei);
    const bool m8  = detect_m8(mask);
    const unsigned char* m8p = (const unsigned char*)mask;
    const int stride = PC * 512;            // edges per sweep of all place chunks

    for (int e0 = (pc * 256 + tid) * 2; e0 < E; e0 += stride) {
      const int ne = min(2, E - e0);
      int d0, d1;
      if (ne == 2) {                        // d-only vector load (aligned)
        if (i64) { int4 b0 = *(const int4*)&ei[2 * (E + e0)]; d0 = b0.x; d1 = b0.z; }
        else     { int2 b0 = *(const int2*)&ei[E + e0];       d0 = b0.x; d1 = b0.y; }
      } else {
        d0 = i64 ? ei[2 * (E + e0)] : ei[E + e0];
        d1 = lo - 1;                        // forces out-of-range
      }
      const bool in0 = (unsigned int)(d0 - lo) < span;
      const bool in1 = (unsigned int)(d1 - lo) < span;
      if (!in0 && !in1) continue;           // ~7/8 of lanes skip mask+src loads

      unsigned int w0e = 0u, w1e = 0u;
      if (in0) w0e = m8 ? (unsigned int)m8p[e0]     : mask[e0];
      if (in1) w1e = m8 ? (unsigned int)m8p[e0 + 1] : mask[e0 + 1];

      if (in0 && w0e != 0u) {
        int s = i64 ? ei[2 * e0] : ei[e0];
        unsigned int pos = atomicAdd(&cnt[d0], 1u);
        if (pos < (unsigned)PAD) pad[(size_t)d0 * PAD + pos] = s;
        else { unsigned int o = atomicAdd(ovfcnt, 1u); ovfbuf[2 * o] = s; ovfbuf[2 * o + 1] = d0; }
      }
      if (in1 && w1e != 0u) {
        int s = i64 ? ei[2 * (e0 + 1)] : ei[e0 + 1];
        unsigned int pos = atomicAdd(&cnt[d1], 1u);
        if (pos < (unsigned)PAD) pad[(size_t)d1 * PAD + pos] = s;
        else { unsigned int o = atomicAdd(ovfcnt, 1u); ovfbuf[2 * o] = s; ovfbuf[2 * o + 1] = d1; }
      }
    }
    return;
  }

  // ---------------- gemm1 branch: tile t = gemmBefore*8 + sub ----------------
  const int t = gemmBefore * 8 + sub;
  const int row0 = t * 32;
  if (row0 >= n) return;
  const int nrows = min(32, n - row0);
  for (int i = tid * 4; i < nrows * DIN; i += 1024)
    *(float4*)&xs[i] = *(const float4*)&x[(size_t)row0 * DIN + i];
  __syncthreads();
  const int col = tid & 63;
  const int wv  = tid >> 6;
  float a[8];
#pragma unroll
  for (int i = 0; i < 8; i++) a[i] = 0.f;
#pragma unroll 4
  for (int k = 0; k < DIN; k++) {
    float w = W1[k * DH + col];              // global, coalesced, L1-hot
#pragma unroll
    for (int i = 0; i < 8; i++)
      a[i] = fmaf(xs[(wv * 8 + i) * DIN + k], w, a[i]);  // LDS broadcast
  }
#pragma unroll
  for (int i = 0; i < 8; i++) {
    int r = row0 + wv * 8 + i;
    if (r < n) g[(size_t)r * DH + col] = a[i];
  }
}

// ---------------- dinv precompute ----------------
__global__ __launch_bounds__(256) void k_dinv(const unsigned int* __restrict__ cnt,
                                              float* __restrict__ dinv, int n) {
  int i = blockIdx.x * 256 + threadIdx.x;
  if (i < n) dinv[i] = rsqrtf((float)cnt[i] + 1.0f);  // +1 = self loop
}

// ---------------- agg(layer1, weighted) + relu/bias + gemm2, barrier-free ----
// One wave per node (r11 shape, r7 math). a = dv*g[v] + sum dinv[s]*g[s];
// u2 = dv*relu(dv*a + b1) premultiplied -> g2 arrives dinv-scaled (commutes
// through linear W2) so aggout needs no per-edge dinv. 64x64 matvec done
// in-register via __shfl broadcast; W2 from global (16 KB, L1-hot).
__global__ __launch_bounds__(256) void k_aggmid(const float* __restrict__ g,
                                                const unsigned int* __restrict__ cnt,
                                                const int* __restrict__ pad,
                                                const float* __restrict__ dinv,
                                                const float* __restrict__ b1,
                                                const float* __restrict__ W2,
                                                const int* __restrict__ ovfbuf,
                                                const unsigned int* __restrict__ ovfcnt,
                                                float* __restrict__ g2, int n) {
  const int v = (blockIdx.x * 256 + threadIdx.x) >> 6;
  if (v >= n) return;
  const int lane = threadIdx.x & 63;
  const float dv = dinv[v];
  const int len = min((int)cnt[v], PAD);
  const int* row = pad + (size_t)v * PAD;
  float a = dv * g[(size_t)v * DH + lane];     // self-loop term
  int e = 0;
  for (; e + 8 <= len; e += 8) {               // 8-deep weighted gather MLP
    int s[8];
#pragma unroll
    for (int j = 0; j < 8; j++) s[j] = row[e + j];
    float w8[8], x8[8];
#pragma unroll
    for (int j = 0; j < 8; j++) w8[j] = dinv[s[j]];
#pragma unroll
    for (int j = 0; j < 8; j++) x8[j] = g[(size_t)s[j] * DH + lane];
#pragma unroll
    for (int j = 0; j < 8; j++) a = fmaf(w8[j], x8[j], a);
  }
  for (; e + 4 <= len; e += 4) {
    int s0 = row[e], s1 = row[e + 1], s2 = row[e + 2], s3 = row[e + 3];
    float w0 = dinv[s0], w1 = dinv[s1], w2 = dinv[s2], w3 = dinv[s3];
    float x0 = g[(size_t)s0 * DH + lane];
    float x1 = g[(size_t)s1 * DH + lane];
    float x2 = g[(size_t)s2 * DH + lane];
    float x3 = g[(size_t)s3 * DH + lane];
    a = fmaf(w0, x0, a); a = fmaf(w1, x1, a);
    a = fmaf(w2, x2, a); a = fmaf(w3, x3, a);
  }
  for (; e < len; e++) {
    int s = row[e];
    a = fmaf(dinv[s], g[(size_t)s * DH + lane], a);
  }
  unsigned int nov = *ovfcnt;                  // normally 0: one scalar load
  if (nov != 0u) {                             // pathological high-degree path
    for (unsigned int j = 0; j < nov; j++) {
      if (ovfbuf[2 * j + 1] == v) {
        int s = ovfbuf[2 * j];
        a = fmaf(dinv[s], g[(size_t)s * DH + lane], a);
      }
    }
  }
  const float u2 = dv * fmaxf(fmaf(dv, a, b1[lane]), 0.f);  // premultiplied

  // in-register 64x64 matvec: g2 row = u2-row @ W2
  float acc = 0.f;
#pragma unroll
  for (int k = 0; k < DH; k++)
    acc = fmaf(__shfl(u2, k, 64), W2[k * DH + lane], acc);
  g2[(size_t)v * DH + lane] = acc;
}

// ---------------- agg(layer2): out = dv*(g2[v] + sum g2[s]) + b2 ------------
// g2 already dinv-premultiplied -> NO per-edge dinv loads.
__global__ __launch_bounds__(256) void k_aggout(const float* __restrict__ g2,
                                                const unsigned int* __restrict__ cnt,
                                                const int* __restrict__ pad,
                                                const float* __restrict__ dinv,
                                                const float* __restrict__ b2,
                                                const int* __restrict__ ovfbuf,
                                                const unsigned int* __restrict__ ovfcnt,
                                                float* __restrict__ out, int n) {
  const int v = (blockIdx.x * 256 + threadIdx.x) >> 6;
  if (v >= n) return;
  const int lane = threadIdx.x & 63;
  const float dv = dinv[v];
  const int len = min((int)cnt[v], PAD);
  const int* row = pad + (size_t)v * PAD;
  float a = g2[(size_t)v * DH + lane];         // self-loop term (pre-scaled)
  int e = 0;
  for (; e + 8 <= len; e += 8) {               // 8-deep gather MLP
    int s[8];
#pragma unroll
    for (int j = 0; j < 8; j++) s[j] = row[e + j];
    float x8[8];
#pragma unroll
    for (int j = 0; j < 8; j++) x8[j] = g2[(size_t)s[j] * DH + lane];
#pragma unroll
    for (int j = 0; j < 8; j++) a += x8[j];
  }
  for (; e + 4 <= len; e += 4) {
    int s0 = row[e], s1 = row[e + 1], s2 = row[e + 2], s3 = row[e + 3];
    float x0 = g2[(size_t)s0 * DH + lane];
    float x1 = g2[(size_t)s1 * DH + lane];
    float x2 = g2[(size_t)s2 * DH + lane];
    float x3 = g2[(size_t)s3 * DH + lane];
    a += x0 + x1 + x2 + x3;
  }
  for (; e < len; e++) a += g2[(size_t)row[e] * DH + lane];
  unsigned int nov = *ovfcnt;
  if (nov != 0u) {
    for (unsigned int j = 0; j < nov; j++) {
      if (ovfbuf[2 * j + 1] == v) a += g2[(size_t)ovfbuf[2 * j] * DH + lane];
    }
  }
  out[(size_t)v * DH + lane] = fmaf(dv, a, b2[lane]);
}

extern "C" void kernel_launch(void* const* d_in, const int* in_sizes, int n_in,
                              void* d_out, int out_size, void* d_ws, size_t ws_size,
                              hipStream_t stream) {
  const float* x  = (const float*)d_in[0];
  const int* ei   = (const int*)d_in[1];
  const unsigned int* mask = (const unsigned int*)d_in[2];
  const float* W1 = (const float*)d_in[3];
  const float* b1 = (const float*)d_in[4];
  const float* W2 = (const float*)d_in[5];
  const float* b2 = (const float*)d_in[6];
  const int n = in_sizes[0] / DIN;     // 50000
  const int E = in_sizes[2];           // 800000

  char* w = (char*)d_ws;
  const size_t A   = 262144u;          // 256 KiB small-array slab
  const size_t BIG = 13631488u;        // 13 MiB >= n*PAD*4 = n*DH*4 = 12.8 MB
  unsigned int* cnt    = (unsigned int*)(w);            // n counters
  unsigned int* ovfcnt = (unsigned int*)(w) + n;        // 1 word after cnt
  float*        dinv   = (float*)(w + A);               // n floats
  int*          pad    = (int*)(w + 2 * A);             // n*PAD ints
  float*        gbuf   = (float*)(w + 2 * A + BIG);     // g1
  float*        g2buf  = (float*)(w + 2 * A + 2 * BIG); // layer-2 gemm output
  int*          ovfbuf = (int*)(w + 2 * A + 3 * BIG);   // spill (worst case E*2)

  (void)hipMemsetAsync(cnt, 0, (size_t)(n + 1) * sizeof(unsigned int), stream);

  const int ntiles = (n + 31) / 32;         // 1563 gemm1 tiles
  const int GC = (ntiles + 7) / 8;          // gemm chunks (8 tiles each)
  const int PC = 391;                       // place chunks: 8 ranges x 391 blocks
  const int aggBlocks = (n * 64 + 255) / 256;   // one wave per node

  // fused XCD-partitioned CSR build + gemm1 (r7 structure, best measured)
  k_fused<<<(PC + GC) * 8, 256, 0, stream>>>(x, W1, ei, mask, E, cnt, pad,
                                             ovfbuf, ovfcnt, gbuf, n, PC, GC);
  k_dinv<<<(n + 255) / 256, 256, 0, stream>>>(cnt, dinv, n);
  // layer 1 weighted aggregation + bias/relu + gemm2, barrier-free
  k_aggmid<<<aggBlocks, 256, 0, stream>>>(gbuf, cnt, pad, dinv, b1, W2,
                                          ovfbuf, ovfcnt, g2buf, n);
  // layer 2 aggregation + b2 -> out
  k_aggout<<<aggBlocks, 256, 0, stream>>>(g2buf, cnt, pad, dinv, b2,
                                          ovfbuf, ovfcnt, (float*)d_out, n);
}

// Round 14
// 141.404 us; speedup vs baseline: 3.3240x; 1.0064x over previous
//
#include <hip/hip_runtime.h>

#define DIN 128
#define DH  64
#define PAD 64

// ---------------- input-format detection ----------------
__device__ __forceinline__ bool detect_i64(const int* __restrict__ ei) {
  bool i64 = true;
#pragma unroll
  for (int j = 1; j < 32; j += 2) i64 = i64 && (ei[j] == 0);
  return i64;
}
__device__ __forceinline__ bool detect_m8(const unsigned int* __restrict__ mask) {
  return (mask[0] == 0x01010101u) && (mask[1] == 0x01010101u);
}

// ---------------- fused: XCD-partitioned placement | gemm1 (r7 best) --------
// Place chunk (sub=blockIdx&7 == XCD under round-robin dispatch): handles dst
// range [sub*n/8,(sub+1)*n/8); loads only dst words up front, mask/src
// exec-masked for in-range edges. pos = atomicAdd(&cnt[d],1) builds padded
// CSR + degree in one pass. Floor = 800K device-scope atomic RMW (~55us,
// proven occupancy/cache/compaction-insensitive r4-r12); gemm1 rides under.
__global__ __launch_bounds__(256) void k_fused(const float* __restrict__ x,
                                               const float* __restrict__ W1,
                                               const int* __restrict__ ei,
                                               const unsigned int* __restrict__ mask,
                                               int E,
                                               unsigned int* __restrict__ cnt,
                                               int* __restrict__ pad,
                                               int* __restrict__ ovfbuf,
                                               unsigned int* __restrict__ ovfcnt,
                                               float* __restrict__ g,
                                               int n, int PC, int GC) {
  __shared__ float xs[32 * DIN];   // 16 KB (gemm branch only)
  const int tid = threadIdx.x;
  const int c   = (int)blockIdx.x >> 3;     // chunk index
  const int sub = (int)blockIdx.x & 7;      // position in chunk == XCD (heuristic)
  const int T = PC + GC;
  const int gemmBefore = (int)(((long long)c * GC) / T);
  const bool isGemm = (int)(((long long)(c + 1) * GC) / T) > gemmBefore;

  if (!isGemm) {
    // ---------------- placement branch: dst range r = sub ----------------
    const int pc = c - gemmBefore;          // place-chunk index in [0, PC)
    const int lo = (int)(((long long)sub * n) >> 3);
    const int hi = (int)(((long long)(sub + 1) * n) >> 3);
    const unsigned int span = (unsigned int)(hi - lo);
    const bool i64 = detect_i64(ei);
    const bool m8  = detect_m8(mask);
    const unsigned char* m8p = (const unsigned char*)mask;
    const int stride = PC * 512;            // edges per sweep of all place chunks

    for (int e0 = (pc * 256 + tid) * 2; e0 < E; e0 += stride) {
      const int ne = min(2, E - e0);
      int d0, d1;
      if (ne == 2) {                        // d-only vector load (aligned)
        if (i64) { int4 b0 = *(const int4*)&ei[2 * (E + e0)]; d0 = b0.x; d1 = b0.z; }
        else     { int2 b0 = *(const int2*)&ei[E + e0];       d0 = b0.x; d1 = b0.y; }
      } else {
        d0 = i64 ? ei[2 * (E + e0)] : ei[E + e0];
        d1 = lo - 1;                        // forces out-of-range
      }
      const bool in0 = (unsigned int)(d0 - lo) < span;
      const bool in1 = (unsigned int)(d1 - lo) < span;
      if (!in0 && !in1) continue;           // ~7/8 of lanes skip mask+src loads

      unsigned int w0e = 0u, w1e = 0u;
      if (in0) w0e = m8 ? (unsigned int)m8p[e0]     : mask[e0];
      if (in1) w1e = m8 ? (unsigned int)m8p[e0 + 1] : mask[e0 + 1];

      if (in0 && w0e != 0u) {
        int s = i64 ? ei[2 * e0] : ei[e0];
        unsigned int pos = atomicAdd(&cnt[d0], 1u);
        if (pos < (unsigned)PAD) pad[(size_t)d0 * PAD + pos] = s;
        else { unsigned int o = atomicAdd(ovfcnt, 1u); ovfbuf[2 * o] = s; ovfbuf[2 * o + 1] = d0; }
      }
      if (in1 && w1e != 0u) {
        int s = i64 ? ei[2 * (e0 + 1)] : ei[e0 + 1];
        unsigned int pos = atomicAdd(&cnt[d1], 1u);
        if (pos < (unsigned)PAD) pad[(size_t)d1 * PAD + pos] = s;
        else { unsigned int o = atomicAdd(ovfcnt, 1u); ovfbuf[2 * o] = s; ovfbuf[2 * o + 1] = d1; }
      }
    }
    return;
  }

  // ---------------- gemm1 branch: tile t = gemmBefore*8 + sub ----------------
  const int t = gemmBefore * 8 + sub;
  const int row0 = t * 32;
  if (row0 >= n) return;
  const int nrows = min(32, n - row0);
  for (int i = tid * 4; i < nrows * DIN; i += 1024)
    *(float4*)&xs[i] = *(const float4*)&x[(size_t)row0 * DIN + i];
  __syncthreads();
  const int col = tid & 63;
  const int wv  = tid >> 6;
  float a[8];
#pragma unroll
  for (int i = 0; i < 8; i++) a[i] = 0.f;
#pragma unroll 4
  for (int k = 0; k < DIN; k++) {
    float w = W1[k * DH + col];              // global, coalesced, L1-hot
#pragma unroll
    for (int i = 0; i < 8; i++)
      a[i] = fmaf(xs[(wv * 8 + i) * DIN + k], w, a[i]);  // LDS broadcast
  }
#pragma unroll
  for (int i = 0; i < 8; i++) {
    int r = row0 + wv * 8 + i;
    if (r < n) g[(size_t)r * DH + col] = a[i];
  }
}

// ---------------- dinv precompute ----------------
__global__ __launch_bounds__(256) void k_dinv(const unsigned int* __restrict__ cnt,
                                              float* __restrict__ dinv, int n) {
  int i = blockIdx.x * 256 + threadIdx.x;
  if (i < n) dinv[i] = rsqrtf((float)cnt[i] + 1.0f);  // +1 = self loop
}

// ---------------- agg(layer1, weighted) + relu/bias + gemm2, barrier-free ----
// One wave per node. a = dv*g[v] + sum dinv[s]*g[s];
// u2 = dv*relu(dv*a + b1) premultiplied -> g2 arrives dinv-scaled (commutes
// through linear W2) so aggout needs no per-edge dinv. 64x64 matvec done
// in-register via v_readlane broadcast (compile-time lane index; scalar path,
// NO ds_bpermute -- the __shfl version cost ~800K DS ops across the grid).
// W2 from global (16 KB, L1-hot). Zero LDS, zero barriers.
__global__ __launch_bounds__(256) void k_aggmid(const float* __restrict__ g,
                                                const unsigned int* __restrict__ cnt,
                                                const int* __restrict__ pad,
                                                const float* __restrict__ dinv,
                                                const float* __restrict__ b1,
                                                const float* __restrict__ W2,
                                                const int* __restrict__ ovfbuf,
                                                const unsigned int* __restrict__ ovfcnt,
                                                float* __restrict__ g2, int n) {
  const int v = (blockIdx.x * 256 + threadIdx.x) >> 6;
  if (v >= n) return;                          // wave-uniform exit: all lanes live
  const int lane = threadIdx.x & 63;
  const float dv = dinv[v];
  const int len = min((int)cnt[v], PAD);
  const int* row = pad + (size_t)v * PAD;
  float a = dv * g[(size_t)v * DH + lane];     // self-loop term
  int e = 0;
  for (; e + 8 <= len; e += 8) {               // 8-deep weighted gather MLP
    int s[8];
#pragma unroll
    for (int j = 0; j < 8; j++) s[j] = row[e + j];
    float w8[8], x8[8];
#pragma unroll
    for (int j = 0; j < 8; j++) w8[j] = dinv[s[j]];
#pragma unroll
    for (int j = 0; j < 8; j++) x8[j] = g[(size_t)s[j] * DH + lane];
#pragma unroll
    for (int j = 0; j < 8; j++) a = fmaf(w8[j], x8[j], a);
  }
  for (; e + 4 <= len; e += 4) {
    int s0 = row[e], s1 = row[e + 1], s2 = row[e + 2], s3 = row[e + 3];
    float w0 = dinv[s0], w1 = dinv[s1], w2 = dinv[s2], w3 = dinv[s3];
    float x0 = g[(size_t)s0 * DH + lane];
    float x1 = g[(size_t)s1 * DH + lane];
    float x2 = g[(size_t)s2 * DH + lane];
    float x3 = g[(size_t)s3 * DH + lane];
    a = fmaf(w0, x0, a); a = fmaf(w1, x1, a);
    a = fmaf(w2, x2, a); a = fmaf(w3, x3, a);
  }
  for (; e < len; e++) {
    int s = row[e];
    a = fmaf(dinv[s], g[(size_t)s * DH + lane], a);
  }
  unsigned int nov = *ovfcnt;                  // normally 0: one scalar load
  if (nov != 0u) {                             // pathological high-degree path
    for (unsigned int j = 0; j < nov; j++) {
      if (ovfbuf[2 * j + 1] == v) {
        int s = ovfbuf[2 * j];
        a = fmaf(dinv[s], g[(size_t)s * DH + lane], a);
      }
    }
  }
  const float u2 = dv * fmaxf(fmaf(dv, a, b1[lane]), 0.f);  // premultiplied

  // in-register 64x64 matvec via scalar readlane broadcast (k is literal)
  const int u2i = __float_as_int(u2);
  float acc = 0.f;
#pragma unroll
  for (int k = 0; k < DH; k++)
    acc = fmaf(__int_as_float(__builtin_amdgcn_readlane(u2i, k)),
               W2[k * DH + lane], acc);
  g2[(size_t)v * DH + lane] = acc;
}

// ---------------- agg(layer2): out = dv*(g2[v] + sum g2[s]) + b2 ------------
// g2 already dinv-premultiplied -> NO per-edge dinv loads.
__global__ __launch_bounds__(256) void k_aggout(const float* __restrict__ g2,
                                                const unsigned int* __restrict__ cnt,
                                                const int* __restrict__ pad,
                                                const float* __restrict__ dinv,
                                                const float* __restrict__ b2,
                                                const int* __restrict__ ovfbuf,
                                                const unsigned int* __restrict__ ovfcnt,
                                                float* __restrict__ out, int n) {
  const int v = (blockIdx.x * 256 + threadIdx.x) >> 6;
  if (v >= n) return;
  const int lane = threadIdx.x & 63;
  const float dv = dinv[v];
  const int len = min((int)cnt[v], PAD);
  const int* row = pad + (size_t)v * PAD;
  float a = g2[(size_t)v * DH + lane];         // self-loop term (pre-scaled)
  int e = 0;
  for (; e + 8 <= len; e += 8) {               // 8-deep gather MLP
    int s[8];
#pragma unroll
    for (int j = 0; j < 8; j++) s[j] = row[e + j];
    float x8[8];
#pragma unroll
    for (int j = 0; j < 8; j++) x8[j] = g2[(size_t)s[j] * DH + lane];
#pragma unroll
    for (int j = 0; j < 8; j++) a += x8[j];
  }
  for (; e + 4 <= len; e += 4) {
    int s0 = row[e], s1 = row[e + 1], s2 = row[e + 2], s3 = row[e + 3];
    float x0 = g2[(size_t)s0 * DH + lane];
    float x1 = g2[(size_t)s1 * DH + lane];
    float x2 = g2[(size_t)s2 * DH + lane];
    float x3 = g2[(size_t)s3 * DH + lane];
    a += x0 + x1 + x2 + x3;
  }
  for (; e < len; e++) a += g2[(size_t)row[e] * DH + lane];
  unsigned int nov = *ovfcnt;
  if (nov != 0u) {
    for (unsigned int j = 0; j < nov; j++) {
      if (ovfbuf[2 * j + 1] == v) a += g2[(size_t)ovfbuf[2 * j] * DH + lane];
    }
  }
  out[(size_t)v * DH + lane] = fmaf(dv, a, b2[lane]);
}

extern "C" void kernel_launch(void* const* d_in, const int* in_sizes, int n_in,
                              void* d_out, int out_size, void* d_ws, size_t ws_size,
                              hipStream_t stream) {
  const float* x  = (const float*)d_in[0];
  const int* ei   = (const int*)d_in[1];
  const unsigned int* mask = (const unsigned int*)d_in[2];
  const float* W1 = (const float*)d_in[3];
  const float* b1 = (const float*)d_in[4];
  const float* W2 = (const float*)d_in[5];
  const float* b2 = (const float*)d_in[6];
  const int n = in_sizes[0] / DIN;     // 50000
  const int E = in_sizes[2];           // 800000

  char* w = (char*)d_ws;
  const size_t A   = 262144u;          // 256 KiB small-array slab
  const size_t BIG = 13631488u;        // 13 MiB >= n*PAD*4 = n*DH*4 = 12.8 MB
  unsigned int* cnt    = (unsigned int*)(w);            // n counters
  unsigned int* ovfcnt = (unsigned int*)(w) + n;        // 1 word after cnt
  float*        dinv   = (float*)(w + A);               // n floats
  int*          pad    = (int*)(w + 2 * A);             // n*PAD ints
  float*        gbuf   = (float*)(w + 2 * A + BIG);     // g1
  float*        g2buf  = (float*)(w + 2 * A + 2 * BIG); // layer-2 gemm output
  int*          ovfbuf = (int*)(w + 2 * A + 3 * BIG);   // spill (worst case E*2)

  (void)hipMemsetAsync(cnt, 0, (size_t)(n + 1) * sizeof(unsigned int), stream);

  const int ntiles = (n + 31) / 32;         // 1563 gemm1 tiles
  const int GC = (ntiles + 7) / 8;          // gemm chunks (8 tiles each)
  const int PC = 391;                       // place chunks: 8 ranges x 391 blocks
  const int aggBlocks = (n * 64 + 255) / 256;   // one wave per node

  // fused XCD-partitioned CSR build + gemm1 (r7 structure, best measured)
  k_fused<<<(PC + GC) * 8, 256, 0, stream>>>(x, W1, ei, mask, E, cnt, pad,
                                             ovfbuf, ovfcnt, gbuf, n, PC, GC);
  k_dinv<<<(n + 255) / 256, 256, 0, stream>>>(cnt, dinv, n);
  // layer 1 weighted aggregation + bias/relu + gemm2 (readlane matvec)
  k_aggmid<<<aggBlocks, 256, 0, stream>>>(gbuf, cnt, pad, dinv, b1, W2,
                                          ovfbuf, ovfcnt, g2buf, n);
  // layer 2 aggregation + b2 -> out
  k_aggout<<<aggBlocks, 256, 0, stream>>>(g2buf, cnt, pad, dinv, b2,
                                          ovfbuf, ovfcnt, (float*)d_out, n);
}